// Round 9
// baseline (246.504 us; speedup 1.0000x reference)
//
#include <hip/hip_runtime.h>
#include <hip/hip_bf16.h>
#include <stdint.h>

// TransformerBlock: B=2 T=2048 D=1024 H=16 HD=64 FF=4096, causal, pre-LN.
// GEMMs + attention in bf16 MFMA (16x16x32), f32 accum, f32 residual path.

typedef __attribute__((ext_vector_type(8))) __bf16 bf16x8;
typedef __attribute__((ext_vector_type(4))) __bf16 bf16x4;
typedef __attribute__((ext_vector_type(4))) float  f32x4;

#define DD    1024
#define TSEQ  2048
#define NTOK  4096
#define FFD   4096

#define ASM_VMCNT0() asm volatile("s_waitcnt vmcnt(0)" ::: "memory")

__device__ __forceinline__ void gll16(const void* g, void* l) {
  __builtin_amdgcn_global_load_lds(
      (const __attribute__((address_space(1))) unsigned int*)g,
      (__attribute__((address_space(3))) unsigned int*)l, 16, 0, 0);
}

__device__ __forceinline__ float gelu_f(float v) {
  float u = 0.7978845608028654f * (v + 0.044715f * v * v * v);
  float t = 1.0f - 2.0f / (1.0f + __expf(2.0f * u));   // tanh(u)
  return 0.5f * v * (1.0f + t);
}

// ---------------- weight f32 -> bf16 convert ----------------
__global__ __launch_bounds__(256) void cvt_weights(
    const float* __restrict__ wq, const float* __restrict__ wk,
    const float* __restrict__ wv, const float* __restrict__ wo,
    const float* __restrict__ w1, const float* __restrict__ w2,
    __bf16* __restrict__ dst)
{
  size_t i4 = (size_t)blockIdx.x * 256 + threadIdx.x;
  size_t e = i4 * 4;
  const float* src; size_t off;
  if (e < (size_t)4 * 1048576) {
    int sel = (int)(e >> 20);
    src = sel == 0 ? wq : sel == 1 ? wk : sel == 2 ? wv : wo;
    off = e & 1048575;
  } else if (e < (size_t)8 * 1048576) {
    src = w1; off = e - (size_t)4 * 1048576;
  } else {
    src = w2; off = e - (size_t)8 * 1048576;
  }
  float4 v = *(const float4*)(src + off);
  bf16x4 o;
  o[0] = (__bf16)v.x; o[1] = (__bf16)v.y; o[2] = (__bf16)v.z; o[3] = (__bf16)v.w;
  *(bf16x4*)(dst + e) = o;
}

// ---------------- LayerNorm: one wave per row ----------------
__global__ __launch_bounds__(256) void ln_kernel(
    const float* __restrict__ x, const float* __restrict__ gw,
    const float* __restrict__ sw, __bf16* __restrict__ out)
{
  const int row  = blockIdx.x * 4 + (threadIdx.x >> 6);
  const int lane = threadIdx.x & 63;
  const float4* xr = (const float4*)(x + (size_t)row * DD);
  float4 v[4];
  float s = 0.f, sq = 0.f;
#pragma unroll
  for (int i = 0; i < 4; ++i) {
    v[i] = xr[i * 64 + lane];
    s  += v[i].x + v[i].y + v[i].z + v[i].w;
    sq += v[i].x * v[i].x + v[i].y * v[i].y + v[i].z * v[i].z + v[i].w * v[i].w;
  }
#pragma unroll
  for (int off = 32; off >= 1; off >>= 1) {
    s  += __shfl_xor(s, off);
    sq += __shfl_xor(sq, off);
  }
  const float mean = s * (1.f / DD);
  const float rstd = rsqrtf(sq * (1.f / DD) - mean * mean + 1e-5f);
  const float4* gr = (const float4*)gw;
  const float4* sr = (const float4*)sw;
#pragma unroll
  for (int i = 0; i < 4; ++i) {
    float4 gv = gr[i * 64 + lane];
    float4 sv = sr[i * 64 + lane];
    bf16x4 o;
    o[0] = (__bf16)(gv.x * (v[i].x - mean) * rstd + sv.x);
    o[1] = (__bf16)(gv.y * (v[i].y - mean) * rstd + sv.y);
    o[2] = (__bf16)(gv.z * (v[i].z - mean) * rstd + sv.z);
    o[3] = (__bf16)(gv.w * (v[i].w - mean) * rstd + sv.w);
    *(bf16x4*)&out[(size_t)row * DD + (size_t)(i * 64 + lane) * 4] = o;
  }
}

// ================= m97-faithful 128x128 GEMM, TLP-first =================
// C[M,N] = A[M,K(lda)] @ Bw[N,K(ldb)]^T. 256 thr / 4 waves (2x2), BK=64.
// SINGLE 32KB LDS buffer -> 4-5 blocks/CU co-resident; cross-block wave
// overlap hides the stage/drain (m114/m97 evidence). Per K-tile:
// 8 gll16 -> syncthreads -> 16 swizzled ds_read_b128 + 32 MFMA -> syncthreads.
// __launch_bounds__(256,4): 16 waves/CU target, VGPR capped <=128.
// MODE: 0=QKV (bf16, V transposed to voutT, Q scaled 1/8),
//       1=bias+gelu bf16, 2=bf16 split-K partial.
template<int MODE>
__global__ __launch_bounds__(256, 4)
void gemm128(const __bf16* __restrict__ A, int lda,
             const __bf16* __restrict__ Bw, int ldb,
             __bf16* __restrict__ Cout, const float* __restrict__ bias,
             __bf16* __restrict__ voutT, int M, int N, int K)
{
  __shared__ __bf16 sm[16384];          // A 16KB | B 16KB
  const int t = threadIdx.x;
  const int lane = t & 63;
  const int l15 = lane & 15, g = lane >> 4;
  const int w = t >> 6;
  const int wr = w >> 1, wc = w & 1;    // 2 x 2 wave grid
  const int m0 = blockIdx.y * 128, n0 = blockIdx.x * 128;

  if (MODE == 2) {                      // split-K offsets
    const int kz = blockIdx.z;
    A    += (size_t)kz * 1024;
    Bw   += (size_t)kz * 1024;
    Cout += (size_t)kz * (size_t)M * N;
  }

  // staging: thread covers rows {i*32+srow}, chunk schunk; source chunk
  // XOR-swizzled (row&7 == srow&7 -> thread-constant).
  const int srow = t >> 3;              // 0..31
  const int schunk = t & 7;
  const int gc = schunk ^ (srow & 7);
  const __bf16* gA = A  + (size_t)(m0 + srow) * lda + gc * 8;
  const __bf16* gB = Bw + (size_t)(n0 + srow) * ldb + gc * 8;
  char* smb = (char*)sm;
  const int sdst = t * 16;

  // fragment read bases (bytes); frag row&7 == l15&7 -> thread-constant XOR.
  const int xa = l15 & 7;
  const int rA = (wr * 64 + l15) * 128;
  const int rB = 16384 + (wc * 64 + l15) * 128;
  const int baseA0 = rA + ((g ^ xa) << 4);
  const int baseA1 = rA + (((4 + g) ^ xa) << 4);
  const int baseB0 = rB + ((g ^ xa) << 4);
  const int baseB1 = rB + (((4 + g) ^ xa) << 4);

  f32x4 acc[4][4] = {};
  const int NT = K >> 6;

  for (int kt = 0; kt < NT; ++kt) {
    const __bf16* a = gA + kt * 64;
    const __bf16* b = gB + kt * 64;
#pragma unroll
    for (int i = 0; i < 4; ++i)
      gll16(a + (size_t)i * 32 * lda, smb + i * 4096 + sdst);
#pragma unroll
    for (int i = 0; i < 4; ++i)
      gll16(b + (size_t)i * 32 * ldb, smb + 16384 + i * 4096 + sdst);
    __syncthreads();                    // drains vmcnt -> tile resident

    bf16x8 af[4][2], bfr[4][2];
#pragma unroll
    for (int mi = 0; mi < 4; ++mi) {
      af[mi][0] = *(const bf16x8*)(smb + baseA0 + mi * 2048);
      af[mi][1] = *(const bf16x8*)(smb + baseA1 + mi * 2048);
    }
#pragma unroll
    for (int ni = 0; ni < 4; ++ni) {
      bfr[ni][0] = *(const bf16x8*)(smb + baseB0 + ni * 2048);
      bfr[ni][1] = *(const bf16x8*)(smb + baseB1 + ni * 2048);
    }
#pragma unroll
    for (int ks = 0; ks < 2; ++ks)
#pragma unroll
      for (int mi = 0; mi < 4; ++mi)
#pragma unroll
        for (int ni = 0; ni < 4; ++ni)
          acc[mi][ni] = __builtin_amdgcn_mfma_f32_16x16x32_bf16(
              af[mi][ks], bfr[ni][ks], acc[mi][ni], 0, 0, 0);

    __syncthreads();                    // all reads done before restage
  }

  // epilogue: C/D frag layout col = lane&15, row = 4*(lane>>4)+r
#pragma unroll
  for (int mi = 0; mi < 4; ++mi) {
    const int rr0 = m0 + wr * 64 + mi * 16 + 4 * g;
#pragma unroll
    for (int ni = 0; ni < 4; ++ni) {
      const int cc = n0 + wc * 64 + ni * 16 + l15;
      if (MODE == 0 && n0 >= 2048) {
        // V: write transposed vT[b][h][d][t], 4 consecutive tokens vectorized
        const int b  = rr0 >> 11;
        const int t0 = rr0 & 2047;
        const int vc = cc - 2048;
        const int h = vc >> 6, d = vc & 63;
        bf16x4 o;
        o[0] = (__bf16)acc[mi][ni][0]; o[1] = (__bf16)acc[mi][ni][1];
        o[2] = (__bf16)acc[mi][ni][2]; o[3] = (__bf16)acc[mi][ni][3];
        *(bf16x4*)&voutT[(((size_t)(b * 16 + h)) * 64 + d) * 2048 + t0] = o;
      } else {
        const int ldc = (MODE == 0) ? 2048 : N;
#pragma unroll
        for (int r = 0; r < 4; ++r) {
          float v = acc[mi][ni][r];
          if (MODE == 0 && cc < 1024) v *= 0.125f;   // fold 1/sqrt(HD) into Q
          if (MODE == 1) { v += bias[cc]; v = gelu_f(v); }
          Cout[(size_t)(rr0 + r) * ldc + cc] = (__bf16)v;
        }
      }
    }
  }
}

// ---------------- FF2 reduce: out = x2 + b2 + sum(partials) ----------------
// out has 4,194,304 elements; 256 thr x 4 elems -> EXACTLY 4096 blocks.
__global__ __launch_bounds__(256) void ff2_reduce(
    const __bf16* __restrict__ part, const float* __restrict__ x2,
    const float* __restrict__ b2, float* __restrict__ out)
{
  const size_t e = ((size_t)blockIdx.x * 256 + threadIdx.x) * 4;
  float4 r = *(const float4*)(x2 + e);
  const float4 b = *(const float4*)(b2 + (e & 1023));
  r.x += b.x; r.y += b.y; r.z += b.z; r.w += b.w;
#pragma unroll
  for (int s = 0; s < 4; ++s) {
    bf16x4 p = *(const bf16x4*)(part + (size_t)s * 4194304 + e);
    r.x += (float)p[0]; r.y += (float)p[1]; r.z += (float)p[2]; r.w += (float)p[3];
  }
  *(float4*)(out + e) = r;
}

// ---------------- legacy 128x128 GEMM (WO only) ----------------
template<bool BIAS, bool RES>
__global__ __launch_bounds__(256, 3)
void gemm_bt(const __bf16* __restrict__ A, const __bf16* __restrict__ Bw,
             float* __restrict__ Cout, const float* __restrict__ bias,
             const float* __restrict__ res, int M, int N, int K)
{
  __shared__ __bf16 As[128 * 64];
  __shared__ __bf16 Bs[128 * 64];
  const int t    = threadIdx.x;
  const int lane = t & 63;
  const int l15  = lane & 15;
  const int g    = lane >> 4;
  const int w    = t >> 6;
  const int wr   = w >> 1, wc = w & 1;
  const int m0 = blockIdx.y * 128;
  const int n0 = blockIdx.x * 128;
  const int srow = t >> 3;
  const int scol = (t & 7) * 8;

  f32x4 acc[4][4] = {};
  const __bf16* Ap = A  + (size_t)m0 * K;
  const __bf16* Bp = Bw + (size_t)n0 * K;

  for (int k0 = 0; k0 < K; k0 += 64) {
#pragma unroll
    for (int i = 0; i < 4; ++i) {
      const int row = i * 32 + srow;
      gll16(Ap + (size_t)row * K + k0 + scol, &As[row * 64 + scol]);
    }
#pragma unroll
    for (int i = 0; i < 4; ++i) {
      const int row = i * 32 + srow;
      gll16(Bp + (size_t)row * K + k0 + scol, &Bs[row * 64 + scol]);
    }
    __syncthreads();
#pragma unroll
    for (int ks = 0; ks < 2; ++ks) {
      bf16x8 af[4], bfr[4];
#pragma unroll
      for (int mi = 0; mi < 4; ++mi)
        af[mi] = *(const bf16x8*)&As[(wr * 64 + mi * 16 + l15) * 64 + ks * 32 + g * 8];
#pragma unroll
      for (int ni = 0; ni < 4; ++ni)
        bfr[ni] = *(const bf16x8*)&Bs[(wc * 64 + ni * 16 + l15) * 64 + ks * 32 + g * 8];
#pragma unroll
      for (int mi = 0; mi < 4; ++mi)
#pragma unroll
        for (int ni = 0; ni < 4; ++ni)
          acc[mi][ni] = __builtin_amdgcn_mfma_f32_16x16x32_bf16(af[mi], bfr[ni], acc[mi][ni], 0, 0, 0);
    }
    __syncthreads();
  }

  const int crow0 = m0 + wr * 64;
  const int ccol0 = n0 + wc * 64;
#pragma unroll
  for (int mi = 0; mi < 4; ++mi) {
#pragma unroll
    for (int r = 0; r < 4; ++r) {
      const int rr = crow0 + mi * 16 + 4 * g + r;
#pragma unroll
      for (int ni = 0; ni < 4; ++ni) {
        const int cc = ccol0 + ni * 16 + l15;
        float v = acc[mi][ni][r];
        if (BIAS) v += bias[cc];
        if (RES)  v += res[(size_t)rr * N + cc];
        Cout[(size_t)rr * N + cc] = v;
      }
    }
  }
}

// ---------------- causal flash attention (unchanged from R7) ----------------
__global__ __launch_bounds__(256, 2)
void attn_kernel(const __bf16* __restrict__ qk, const __bf16* __restrict__ vT,
                 __bf16* __restrict__ ctx)
{
  __shared__ __bf16 Ks[64 * 64];       // [k][d] swizzled
  __shared__ __bf16 VTs[64 * 64];      // [d][k] swizzled
  __shared__ __bf16 Ps[4][16 * 64];    // per-wave P [q][k] swizzled
  const int t    = threadIdx.x;
  const int lane = t & 63;
  const int l15  = lane & 15;
  const int g    = lane >> 4;
  const int w    = t >> 6;
  const int qt = gridDim.x - 1 - blockIdx.x;   // heavy blocks dispatch first
  const int hh = blockIdx.y;
  const int bb = blockIdx.z;
  const int q0 = qt * 64;

  const int qrow = q0 + w * 16 + l15;
  const size_t qkrow = ((size_t)(bb * 2048 + qrow)) * 2048 + hh * 64;
  bf16x8 qf0 = *(const bf16x8*)&qk[qkrow + g * 8];
  bf16x8 qf1 = *(const bf16x8*)&qk[qkrow + 32 + g * 8];

  const int kk = t >> 2;
  const int c0 = (t & 3) * 16;
  const __bf16* kbase = &qk[((size_t)(bb * 2048) + kk) * 2048 + 1024 + hh * 64 + c0];
  const __bf16* vbase = &vT[(((size_t)(bb * 16 + hh)) * 64 + kk) * 2048 + c0];
  const int xw  = (kk & 7) << 4;
  char* kdst = (char*)Ks  + kk * 128;
  char* vdst = (char*)VTs + kk * 128;
  const int cw0 = ((((t & 3) * 2)    ) << 4) ^ xw;
  const int cw1 = ((((t & 3) * 2) + 1) << 4) ^ xw;

  f32x4 acc[4] = {};
  float mrun = -1e30f, lrun = 0.f;

  bf16x8 ka0, ka1, va0, va1, kb0, kb1, vb0, vb1;

  auto LOAD = [&](int kt, bf16x8& k0, bf16x8& k1, bf16x8& v0, bf16x8& v1) {
    const __bf16* kp = kbase + (size_t)kt * 64 * 2048;
    k0 = *(const bf16x8*)(kp);
    k1 = *(const bf16x8*)(kp + 8);
    const __bf16* vp = vbase + kt * 64;
    v0 = *(const bf16x8*)(vp);
    v1 = *(const bf16x8*)(vp + 8);
  };
  auto WRITE = [&](bf16x8& k0, bf16x8& k1, bf16x8& v0, bf16x8& v1) {
    *(bf16x8*)(kdst + cw0) = k0;
    *(bf16x8*)(kdst + cw1) = k1;
    *(bf16x8*)(vdst + cw0) = v0;
    *(bf16x8*)(vdst + cw1) = v1;
  };

  const int xr = (l15 & 7) << 4;
  char* pw = (char*)Ps[w] + l15 * 128;

  auto COMPUTE = [&](int kt) {
    f32x4 s[4];
#pragma unroll
    for (int f = 0; f < 4; ++f) {
      const char* kb = (const char*)Ks + (f * 16 + l15) * 128;
      bf16x8 a0 = *(const bf16x8*)(kb + ((g << 4) ^ xr));
      bf16x8 a1 = *(const bf16x8*)(kb + (((4 + g) << 4) ^ xr));
      f32x4 z = {};
      z = __builtin_amdgcn_mfma_f32_16x16x32_bf16(a0, qf0, z, 0, 0, 0);
      z = __builtin_amdgcn_mfma_f32_16x16x32_bf16(a1, qf1, z, 0, 0, 0);
      s[f] = z;
    }

    float pmax = -1e30f;
    if (kt == qt) {
      const int qg = q0 + w * 16 + l15;
#pragma unroll
      for (int f = 0; f < 4; ++f)
#pragma unroll
        for (int r = 0; r < 4; ++r) {
          const int kg = kt * 64 + f * 16 + g * 4 + r;
          if (kg > qg) s[f][r] = -1e30f;
          pmax = fmaxf(pmax, s[f][r]);
        }
    } else {
#pragma unroll
      for (int f = 0; f < 4; ++f)
#pragma unroll
        for (int r = 0; r < 4; ++r) pmax = fmaxf(pmax, s[f][r]);
    }
    pmax = fmaxf(pmax, __shfl_xor(pmax, 16));
    pmax = fmaxf(pmax, __shfl_xor(pmax, 32));

    if (__any(pmax > mrun)) {
      const float mnew  = fmaxf(mrun, pmax);
      const float alpha = __expf(mrun - mnew);
      float al[4];
#pragma unroll
      for (int r = 0; r < 4; ++r) al[r] = __shfl(alpha, g * 4 + r);
#pragma unroll
      for (int nf = 0; nf < 4; ++nf)
#pragma unroll
        for (int r = 0; r < 4; ++r) acc[nf][r] *= al[r];
      lrun *= alpha;
      mrun = mnew;
    }

    float lsum = 0.f;
#pragma unroll
    for (int f = 0; f < 4; ++f)
#pragma unroll
      for (int r = 0; r < 4; ++r) {
        float p = __expf(s[f][r] - mrun);
        s[f][r] = p;
        lsum += p;
      }
    lsum += __shfl_xor(lsum, 16);
    lsum += __shfl_xor(lsum, 32);
    lrun += lsum;

#pragma unroll
    for (int f = 0; f < 4; ++f) {
      bf16x4 pk;
      pk[0] = (__bf16)s[f][0]; pk[1] = (__bf16)s[f][1];
      pk[2] = (__bf16)s[f][2]; pk[3] = (__bf16)s[f][3];
      *(bf16x4*)(pw + ((((f * 2 + (g >> 1)) << 4) ^ xr) + (g & 1) * 8)) = pk;
    }
    asm volatile("s_waitcnt lgkmcnt(0)" ::: "memory");

#pragma unroll
    for (int ks = 0; ks < 2; ++ks) {
      bf16x8 pa = *(const bf16x8*)(pw + (((ks * 4 + g) << 4) ^ xr));
#pragma unroll
      for (int nf = 0; nf < 4; ++nf) {
        const char* vb = (const char*)VTs + (nf * 16 + l15) * 128;
        bf16x8 vf = *(const bf16x8*)(vb + (((ks * 4 + g) << 4) ^ xr));
        acc[nf] = __builtin_amdgcn_mfma_f32_16x16x32_bf16(pa, vf, acc[nf], 0, 0, 0);
      }
    }
  };

  LOAD(0, ka0, ka1, va0, va1);
  int kt = 0;
  for (;;) {
    ASM_VMCNT0();
    __syncthreads();
    WRITE(ka0, ka1, va0, va1);
    if (kt < qt) LOAD(kt + 1, kb0, kb1, vb0, vb1);
    __syncthreads();
    COMPUTE(kt);
    if (++kt > qt) break;

    ASM_VMCNT0();
    __syncthreads();
    WRITE(kb0, kb1, vb0, vb1);
    if (kt < qt) LOAD(kt + 1, ka0, ka1, va0, va1);
    __syncthreads();
    COMPUTE(kt);
    if (++kt > qt) break;
  }

  float li[4];
#pragma unroll
  for (int r = 0; r < 4; ++r) li[r] = 1.0f / __shfl(lrun, g * 4 + r);
#pragma unroll
  for (int nf = 0; nf < 4; ++nf)
#pragma unroll
    for (int r = 0; r < 4; ++r) {
      const int row = q0 + w * 16 + 4 * g + r;
      ctx[((size_t)(bb * 2048 + row)) * DD + hh * 64 + nf * 16 + l15] =
          (__bf16)(acc[nf][r] * li[r]);
    }
}

// ---------------- launcher ----------------
extern "C" void kernel_launch(void* const* d_in, const int* in_sizes, int n_in,
                              void* d_out, int out_size, void* d_ws, size_t ws_size,
                              hipStream_t stream)
{
  (void)in_sizes; (void)n_in; (void)out_size; (void)ws_size;
  const float* x  = (const float*)d_in[0];
  const float* wq = (const float*)d_in[1];
  const float* wk = (const float*)d_in[2];
  const float* wv = (const float*)d_in[3];
  const float* wo = (const float*)d_in[4];
  const float* bo = (const float*)d_in[5];
  const float* w1 = (const float*)d_in[6];
  const float* b1 = (const float*)d_in[7];
  const float* w2 = (const float*)d_in[8];
  const float* b2 = (const float*)d_in[9];
  const float* g1 = (const float*)d_in[10];
  const float* s1 = (const float*)d_in[11];
  const float* g2 = (const float*)d_in[12];
  const float* s2 = (const float*)d_in[13];
  float* out = (float*)d_out;

  char* ws = (char*)d_ws;
  __bf16* wbf  = (__bf16*)ws;                         // 24MB weights (q,k,v,o,w1,w2)
  __bf16* hbuf = (__bf16*)(ws + 25165824);            // 8MB
  __bf16* qkb  = (__bf16*)(ws + 33554432);            // 16MB, Q|K [4096][2048]
  __bf16* vbT  = (__bf16*)(ws + 50331648);            // 8MB,  V^T [2][16][64][2048]
  __bf16* ctxb = (__bf16*)(ws + 58720256);            // 8MB
  float*  x2   = (float*)(ws + 67108864);             // 16MB
  __bf16* ffb  = (__bf16*)(ws + 83886080);            // 32MB
  __bf16* part = (__bf16*)(ws + 33554432);            // 32MB, overlaps qkb..ctxb (dead post-WO)

  cvt_weights<<<12288, 256, 0, stream>>>(wq, wk, wv, wo, w1, w2, wbf);
  ln_kernel<<<1024, 256, 0, stream>>>(x, g1, s1, hbuf);

  // fused QKV: M=4096 N=3072 K=1024, 768 blocks (~3/CU)
  gemm128<0><<<dim3(24, 32), 256, 0, stream>>>(
      hbuf, 1024, wbf, 1024, qkb, nullptr, vbT, NTOK, 3072, 1024);

  dim3 ga(32, 16, 2);
  attn_kernel<<<ga, 256, 0, stream>>>(qkb, vbT, ctxb);

  // WO: M=4096 N=1024 K=1024 (+bo, +x residual, f32)
  gemm_bt<true, true><<<dim3(8, 32), 256, 0, stream>>>(
      ctxb, wbf + 3145728, x2, bo, x, NTOK, DD, DD);
  ln_kernel<<<1024, 256, 0, stream>>>(x2, g2, s2, hbuf);

  // FF1: M=4096 N=4096 K=1024, 1024 blocks (4/CU), bias+gelu -> bf16
  gemm128<1><<<dim3(32, 32), 256, 0, stream>>>(
      hbuf, 1024, wbf + 4194304, 1024, ffb, b1, nullptr, NTOK, FFD, 1024);

  // FF2 split-K (KS=4): 1024 blocks (4/CU), bf16 partials + fused reduce
  gemm128<2><<<dim3(8, 32, 4), 256, 0, stream>>>(
      ffb, 4096, wbf + 8388608, 4096, part, nullptr, nullptr, NTOK, DD, 1024);
  ff2_reduce<<<4096, 256, 0, stream>>>(part, x2, b2, out);
}

// Round 10
// 219.081 us; speedup vs baseline: 1.1252x; 1.1252x over previous
//
#include <hip/hip_runtime.h>
#include <hip/hip_bf16.h>
#include <stdint.h>

// TransformerBlock: B=2 T=2048 D=1024 H=16 HD=64 FF=4096, causal, pre-LN.
// GEMMs + attention in bf16 MFMA (16x16x32), f32 accum, f32 residual path.

typedef __attribute__((ext_vector_type(8))) __bf16 bf16x8;
typedef __attribute__((ext_vector_type(4))) __bf16 bf16x4;
typedef __attribute__((ext_vector_type(4))) float  f32x4;

#define DD    1024
#define TSEQ  2048
#define NTOK  4096
#define FFD   4096

#define ASM_VMCNT0() asm volatile("s_waitcnt vmcnt(0)" ::: "memory")

__device__ __forceinline__ void gll16(const void* g, void* l) {
  __builtin_amdgcn_global_load_lds(
      (const __attribute__((address_space(1))) unsigned int*)g,
      (__attribute__((address_space(3))) unsigned int*)l, 16, 0, 0);
}

__device__ __forceinline__ float gelu_f(float v) {
  float u = 0.7978845608028654f * (v + 0.044715f * v * v * v);
  float t = 1.0f - 2.0f / (1.0f + __expf(2.0f * u));   // tanh(u)
  return 0.5f * v * (1.0f + t);
}

// ---------------- weight f32 -> bf16 convert ----------------
__global__ __launch_bounds__(256) void cvt_weights(
    const float* __restrict__ wq, const float* __restrict__ wk,
    const float* __restrict__ wv, const float* __restrict__ wo,
    const float* __restrict__ w1, const float* __restrict__ w2,
    __bf16* __restrict__ dst)
{
  size_t i4 = (size_t)blockIdx.x * 256 + threadIdx.x;
  size_t e = i4 * 4;
  const float* src; size_t off;
  if (e < (size_t)4 * 1048576) {
    int sel = (int)(e >> 20);
    src = sel == 0 ? wq : sel == 1 ? wk : sel == 2 ? wv : wo;
    off = e & 1048575;
  } else if (e < (size_t)8 * 1048576) {
    src = w1; off = e - (size_t)4 * 1048576;
  } else {
    src = w2; off = e - (size_t)8 * 1048576;
  }
  float4 v = *(const float4*)(src + off);
  bf16x4 o;
  o[0] = (__bf16)v.x; o[1] = (__bf16)v.y; o[2] = (__bf16)v.z; o[3] = (__bf16)v.w;
  *(bf16x4*)(dst + e) = o;
}

// ---------------- LayerNorm: one wave per row ----------------
__global__ __launch_bounds__(256) void ln_kernel(
    const float* __restrict__ x, const float* __restrict__ gw,
    const float* __restrict__ sw, __bf16* __restrict__ out)
{
  const int row  = blockIdx.x * 4 + (threadIdx.x >> 6);
  const int lane = threadIdx.x & 63;
  const float4* xr = (const float4*)(x + (size_t)row * DD);
  float4 v[4];
  float s = 0.f, sq = 0.f;
#pragma unroll
  for (int i = 0; i < 4; ++i) {
    v[i] = xr[i * 64 + lane];
    s  += v[i].x + v[i].y + v[i].z + v[i].w;
    sq += v[i].x * v[i].x + v[i].y * v[i].y + v[i].z * v[i].z + v[i].w * v[i].w;
  }
#pragma unroll
  for (int off = 32; off >= 1; off >>= 1) {
    s  += __shfl_xor(s, off);
    sq += __shfl_xor(sq, off);
  }
  const float mean = s * (1.f / DD);
  const float rstd = rsqrtf(sq * (1.f / DD) - mean * mean + 1e-5f);
  const float4* gr = (const float4*)gw;
  const float4* sr = (const float4*)sw;
#pragma unroll
  for (int i = 0; i < 4; ++i) {
    float4 gv = gr[i * 64 + lane];
    float4 sv = sr[i * 64 + lane];
    bf16x4 o;
    o[0] = (__bf16)(gv.x * (v[i].x - mean) * rstd + sv.x);
    o[1] = (__bf16)(gv.y * (v[i].y - mean) * rstd + sv.y);
    o[2] = (__bf16)(gv.z * (v[i].z - mean) * rstd + sv.z);
    o[3] = (__bf16)(gv.w * (v[i].w - mean) * rstd + sv.w);
    *(bf16x4*)&out[(size_t)row * DD + (size_t)(i * 64 + lane) * 4] = o;
  }
}

// ================= T3-minimum 2-phase 256x256 GEMM (R8 winner) =============
// MODE: 0=QKV (bf16, V transposed to voutT, Q scaled 1/8), 1=bias+gelu bf16,
//       2=bf16 split-K partial.
template<int MODE>
__global__ __launch_bounds__(512, 2)
void gemm256(const __bf16* __restrict__ A, int lda,
             const __bf16* __restrict__ Bw, int ldb,
             __bf16* __restrict__ Cout, const float* __restrict__ bias,
             __bf16* __restrict__ voutT, int M, int N, int K)
{
  __shared__ __bf16 sm[65536];          // 2 bufs x (A 32KB | B 32KB)
  const int t = threadIdx.x;
  const int lane = t & 63;
  const int l15 = lane & 15, g = lane >> 4;
  const int w = t >> 6;
  const int wm = w >> 2, wn = w & 3;    // 2 x 4 wave grid
  const int m0 = blockIdx.y * 256, n0 = blockIdx.x * 256;

  if (MODE == 2) {                      // split-K offsets
    const int kz = blockIdx.z;
    A    += (size_t)kz * 1024;
    Bw   += (size_t)kz * 1024;
    Cout += (size_t)kz * (size_t)M * N;
  }

  const int srow = t >> 3;
  const int schunk = t & 7;
  const int gc = schunk ^ (srow & 7);
  const __bf16* gA = A  + (size_t)(m0 + srow) * lda + gc * 8;
  const __bf16* gB = Bw + (size_t)(n0 + srow) * ldb + gc * 8;
  char* smb = (char*)sm;
  const int sdst = t * 16;

  auto STAGE = [&](int kt, int cur) {
    char* dA = smb + cur * 65536;
    char* dB = dA + 32768;
    const __bf16* a = gA + kt * 64;
    const __bf16* b = gB + kt * 64;
#pragma unroll
    for (int i = 0; i < 4; ++i)
      gll16(a + (size_t)i * 64 * lda, dA + i * 8192 + sdst);
#pragma unroll
    for (int i = 0; i < 4; ++i)
      gll16(b + (size_t)i * 64 * ldb, dB + i * 8192 + sdst);
  };

  const int xa = l15 & 7;
  const int baseA0 = (wm * 128 + l15) * 128 + ((g ^ xa) << 4);
  const int baseA1 = (wm * 128 + l15) * 128 + (((4 + g) ^ xa) << 4);
  const int baseB0 = 32768 + (wn * 64 + l15) * 128 + ((g ^ xa) << 4);
  const int baseB1 = 32768 + (wn * 64 + l15) * 128 + (((4 + g) ^ xa) << 4);

  f32x4 acc[8][4] = {};
  const int NT = K >> 6;

  STAGE(0, 0);
  __syncthreads();

  for (int kt = 0; kt < NT; ++kt) {
    const int cur = kt & 1;
    if (kt + 1 < NT) STAGE(kt + 1, cur ^ 1);

    const char* bufb = smb + cur * 65536;
    bf16x8 af[8][2], bfr[4][2];
#pragma unroll
    for (int mi = 0; mi < 8; ++mi) {
      af[mi][0] = *(const bf16x8*)(bufb + baseA0 + mi * 2048);
      af[mi][1] = *(const bf16x8*)(bufb + baseA1 + mi * 2048);
    }
#pragma unroll
    for (int ni = 0; ni < 4; ++ni) {
      bfr[ni][0] = *(const bf16x8*)(bufb + baseB0 + ni * 2048);
      bfr[ni][1] = *(const bf16x8*)(bufb + baseB1 + ni * 2048);
    }
#pragma unroll
    for (int ks = 0; ks < 2; ++ks)
#pragma unroll
      for (int mi = 0; mi < 8; ++mi)
#pragma unroll
        for (int ni = 0; ni < 4; ++ni)
          acc[mi][ni] = __builtin_amdgcn_mfma_f32_16x16x32_bf16(
              af[mi][ks], bfr[ni][ks], acc[mi][ni], 0, 0, 0);

    __syncthreads();
  }

#pragma unroll
  for (int mi = 0; mi < 8; ++mi) {
    const int rr0 = m0 + wm * 128 + mi * 16 + 4 * g;
#pragma unroll
    for (int ni = 0; ni < 4; ++ni) {
      const int cc = n0 + wn * 64 + ni * 16 + l15;
      if (MODE == 0 && n0 + wn * 64 >= 2048) {
        const int b  = rr0 >> 11;
        const int t0 = rr0 & 2047;
        const int vc = cc - 2048;
        const int h = vc >> 6, d = vc & 63;
        bf16x4 o;
        o[0] = (__bf16)acc[mi][ni][0]; o[1] = (__bf16)acc[mi][ni][1];
        o[2] = (__bf16)acc[mi][ni][2]; o[3] = (__bf16)acc[mi][ni][3];
        *(bf16x4*)&voutT[(((size_t)(b * 16 + h)) * 64 + d) * 2048 + t0] = o;
      } else {
        const int ldc = (MODE == 0) ? 2048 : N;
#pragma unroll
        for (int r = 0; r < 4; ++r) {
          float v = acc[mi][ni][r];
          if (MODE == 0 && cc < 1024) v *= 0.125f;   // fold 1/sqrt(HD) into Q
          if (MODE == 1) { v += bias[cc]; v = gelu_f(v); }
          Cout[(size_t)(rr0 + r) * ldc + cc] = (__bf16)v;
        }
      }
    }
  }
}

// ---------------- FF2 reduce: out = x2 + b2 + sum(partials) ----------------
__global__ __launch_bounds__(256) void ff2_reduce(
    const __bf16* __restrict__ part, const float* __restrict__ x2,
    const float* __restrict__ b2, float* __restrict__ out)
{
  const size_t e = ((size_t)blockIdx.x * 256 + threadIdx.x) * 4;
  float4 r = *(const float4*)(x2 + e);
  const float4 b = *(const float4*)(b2 + (e & 1023));
  r.x += b.x; r.y += b.y; r.z += b.z; r.w += b.w;
#pragma unroll
  for (int s = 0; s < 4; ++s) {
    bf16x4 p = *(const bf16x4*)(part + (size_t)s * 4194304 + e);
    r.x += (float)p[0]; r.y += (float)p[1]; r.z += (float)p[2]; r.w += (float)p[3];
  }
  *(float4*)(out + e) = r;
}

// ---------------- legacy 128x128 GEMM (WO only) ----------------
template<bool BIAS, bool RES>
__global__ __launch_bounds__(256, 3)
void gemm_bt(const __bf16* __restrict__ A, const __bf16* __restrict__ Bw,
             float* __restrict__ Cout, const float* __restrict__ bias,
             const float* __restrict__ res, int M, int N, int K)
{
  __shared__ __bf16 As[128 * 64];
  __shared__ __bf16 Bs[128 * 64];
  const int t    = threadIdx.x;
  const int lane = t & 63;
  const int l15  = lane & 15;
  const int g    = lane >> 4;
  const int w    = t >> 6;
  const int wr   = w >> 1, wc = w & 1;
  const int m0 = blockIdx.y * 128;
  const int n0 = blockIdx.x * 128;
  const int srow = t >> 3;
  const int scol = (t & 7) * 8;

  f32x4 acc[4][4] = {};
  const __bf16* Ap = A  + (size_t)m0 * K;
  const __bf16* Bp = Bw + (size_t)n0 * K;

  for (int k0 = 0; k0 < K; k0 += 64) {
#pragma unroll
    for (int i = 0; i < 4; ++i) {
      const int row = i * 32 + srow;
      gll16(Ap + (size_t)row * K + k0 + scol, &As[row * 64 + scol]);
    }
#pragma unroll
    for (int i = 0; i < 4; ++i) {
      const int row = i * 32 + srow;
      gll16(Bp + (size_t)row * K + k0 + scol, &Bs[row * 64 + scol]);
    }
    __syncthreads();
#pragma unroll
    for (int ks = 0; ks < 2; ++ks) {
      bf16x8 af[4], bfr[4];
#pragma unroll
      for (int mi = 0; mi < 4; ++mi)
        af[mi] = *(const bf16x8*)&As[(wr * 64 + mi * 16 + l15) * 64 + ks * 32 + g * 8];
#pragma unroll
      for (int ni = 0; ni < 4; ++ni)
        bfr[ni] = *(const bf16x8*)&Bs[(wc * 64 + ni * 16 + l15) * 64 + ks * 32 + g * 8];
#pragma unroll
      for (int mi = 0; mi < 4; ++mi)
#pragma unroll
        for (int ni = 0; ni < 4; ++ni)
          acc[mi][ni] = __builtin_amdgcn_mfma_f32_16x16x32_bf16(af[mi], bfr[ni], acc[mi][ni], 0, 0, 0);
    }
    __syncthreads();
  }

  const int crow0 = m0 + wr * 64;
  const int ccol0 = n0 + wc * 64;
#pragma unroll
  for (int mi = 0; mi < 4; ++mi) {
#pragma unroll
    for (int r = 0; r < 4; ++r) {
      const int rr = crow0 + mi * 16 + 4 * g + r;
#pragma unroll
      for (int ni = 0; ni < 4; ++ni) {
        const int cc = ccol0 + ni * 16 + l15;
        float v = acc[mi][ni][r];
        if (BIAS) v += bias[cc];
        if (RES)  v += res[(size_t)rr * N + cc];
        Cout[(size_t)rr * N + cc] = v;
      }
    }
  }
}

// ---------------- attention tile compute (shared by both q-states) ----------
__device__ __forceinline__ void attn_tile(
    int kt, int qt, int qg,
    bf16x8 qf0, bf16x8 qf1,
    f32x4 (&acc)[4], float& mrun, float& lrun,
    char* pw, const char* KsB, const char* VTsB,
    int g, int l15, int xr)
{
  f32x4 s[4];
#pragma unroll
  for (int f = 0; f < 4; ++f) {
    const char* kb = KsB + (f * 16 + l15) * 128;
    bf16x8 a0 = *(const bf16x8*)(kb + ((g << 4) ^ xr));
    bf16x8 a1 = *(const bf16x8*)(kb + (((4 + g) << 4) ^ xr));
    f32x4 z = {};
    z = __builtin_amdgcn_mfma_f32_16x16x32_bf16(a0, qf0, z, 0, 0, 0);
    z = __builtin_amdgcn_mfma_f32_16x16x32_bf16(a1, qf1, z, 0, 0, 0);
    s[f] = z;
  }

  float pmax = -1e30f;
  if (kt == qt) {                        // only diagonal tile masks
#pragma unroll
    for (int f = 0; f < 4; ++f)
#pragma unroll
      for (int r = 0; r < 4; ++r) {
        const int kg = kt * 64 + f * 16 + g * 4 + r;
        if (kg > qg) s[f][r] = -1e30f;
        pmax = fmaxf(pmax, s[f][r]);
      }
  } else {
#pragma unroll
    for (int f = 0; f < 4; ++f)
#pragma unroll
      for (int r = 0; r < 4; ++r) pmax = fmaxf(pmax, s[f][r]);
  }
  pmax = fmaxf(pmax, __shfl_xor(pmax, 16));
  pmax = fmaxf(pmax, __shfl_xor(pmax, 32));

  if (__any(pmax > mrun)) {              // defer-max: skip rescale otherwise
    const float mnew  = fmaxf(mrun, pmax);
    const float alpha = __expf(mrun - mnew);
    float al[4];
#pragma unroll
    for (int r = 0; r < 4; ++r) al[r] = __shfl(alpha, g * 4 + r);
#pragma unroll
    for (int nf = 0; nf < 4; ++nf)
#pragma unroll
      for (int r = 0; r < 4; ++r) acc[nf][r] *= al[r];
    lrun *= alpha;
    mrun = mnew;
  }

  float lsum = 0.f;
#pragma unroll
  for (int f = 0; f < 4; ++f)
#pragma unroll
    for (int r = 0; r < 4; ++r) {
      float p = __expf(s[f][r] - mrun);
      s[f][r] = p;
      lsum += p;
    }
  lsum += __shfl_xor(lsum, 16);
  lsum += __shfl_xor(lsum, 32);
  lrun += lsum;

#pragma unroll
  for (int f = 0; f < 4; ++f) {
    bf16x4 pk;
    pk[0] = (__bf16)s[f][0]; pk[1] = (__bf16)s[f][1];
    pk[2] = (__bf16)s[f][2]; pk[3] = (__bf16)s[f][3];
    *(bf16x4*)(pw + ((((f * 2 + (g >> 1)) << 4) ^ xr) + (g & 1) * 8)) = pk;
  }
  asm volatile("s_waitcnt lgkmcnt(0)" ::: "memory");

#pragma unroll
  for (int ks = 0; ks < 2; ++ks) {
    bf16x8 pa = *(const bf16x8*)(pw + (((ks * 4 + g) << 4) ^ xr));
#pragma unroll
    for (int nf = 0; nf < 4; ++nf) {
      const char* vb = VTsB + (nf * 16 + l15) * 128;
      bf16x8 vf = *(const bf16x8*)(vb + (((ks * 4 + g) << 4) ^ xr));
      acc[nf] = __builtin_amdgcn_mfma_f32_16x16x32_bf16(pa, vf, acc[nf], 0, 0, 0);
    }
  }
}

// ---------------- causal flash attention, paired q-tiles -------------------
// Block (j,h,b) owns q-tiles A=j and B=31-j: every block = exactly 33 tile
// computes (perfect balance). Staged K/V tile serves BOTH states while
// kt <= j -> 26% fewer stage rounds/barriers. grid (16,16,2) = 512 blocks.
__global__ __launch_bounds__(256, 2)
void attn_kernel(const __bf16* __restrict__ qk, const __bf16* __restrict__ vT,
                 __bf16* __restrict__ ctx)
{
  __shared__ __bf16 Ks[64 * 64];        // [k][d] swizzled
  __shared__ __bf16 VTs[64 * 64];       // [d][k] swizzled
  __shared__ __bf16 Ps[4][2][1024];     // per-wave, per-state P [q][k] swizzled
  const int t    = threadIdx.x;
  const int lane = t & 63;
  const int l15  = lane & 15;
  const int g    = lane >> 4;
  const int w    = t >> 6;
  const int j  = blockIdx.x;
  const int qtA = j, qtB = 31 - j;      // qtA < qtB always (j<16)
  const int hh = blockIdx.y;
  const int bb = blockIdx.z;

  // Q fragments for both states (already scaled by 1/8 in QKV epilogue)
  const int qrowA = qtA * 64 + w * 16 + l15;
  const int qrowB = qtB * 64 + w * 16 + l15;
  const size_t qkrA = ((size_t)(bb * 2048 + qrowA)) * 2048 + hh * 64;
  const size_t qkrB = ((size_t)(bb * 2048 + qrowB)) * 2048 + hh * 64;
  bf16x8 qfA0 = *(const bf16x8*)&qk[qkrA + g * 8];
  bf16x8 qfA1 = *(const bf16x8*)&qk[qkrA + 32 + g * 8];
  bf16x8 qfB0 = *(const bf16x8*)&qk[qkrB + g * 8];
  bf16x8 qfB1 = *(const bf16x8*)&qk[qkrB + 32 + g * 8];

  // staging geometry (same as R7): thread (kk=t>>2, c0=(t&3)*16)
  const int kk = t >> 2;
  const int c0 = (t & 3) * 16;
  const __bf16* kbase = &qk[((size_t)(bb * 2048) + kk) * 2048 + 1024 + hh * 64 + c0];
  const __bf16* vbase = &vT[(((size_t)(bb * 16 + hh)) * 64 + kk) * 2048 + c0];
  const int xw  = (kk & 7) << 4;
  char* kdst = (char*)Ks  + kk * 128;
  char* vdst = (char*)VTs + kk * 128;
  const int cw0 = ((((t & 3) * 2)    ) << 4) ^ xw;
  const int cw1 = ((((t & 3) * 2) + 1) << 4) ^ xw;

  f32x4 accA[4] = {}, accB[4] = {};
  float mA = -1e30f, lA = 0.f, mB = -1e30f, lB = 0.f;
  const int qgA = qtA * 64 + w * 16 + l15;
  const int qgB = qtB * 64 + w * 16 + l15;

  bf16x8 ka0, ka1, va0, va1, kb0, kb1, vb0, vb1;

  auto LOAD = [&](int kt, bf16x8& k0, bf16x8& k1, bf16x8& v0, bf16x8& v1) {
    const __bf16* kp = kbase + (size_t)kt * 64 * 2048;
    k0 = *(const bf16x8*)(kp);
    k1 = *(const bf16x8*)(kp + 8);
    const __bf16* vp = vbase + kt * 64;
    v0 = *(const bf16x8*)(vp);
    v1 = *(const bf16x8*)(vp + 8);
  };
  auto WRITE = [&](bf16x8& k0, bf16x8& k1, bf16x8& v0, bf16x8& v1) {
    *(bf16x8*)(kdst + cw0) = k0;
    *(bf16x8*)(kdst + cw1) = k1;
    *(bf16x8*)(vdst + cw0) = v0;
    *(bf16x8*)(vdst + cw1) = v1;
  };

  const int xr = (l15 & 7) << 4;
  char* pwA = (char*)&Ps[w][0][0] + l15 * 128;
  char* pwB = (char*)&Ps[w][1][0] + l15 * 128;
  const char* KsB  = (const char*)Ks;
  const char* VTsB = (const char*)VTs;

  const int NT = qtB + 1;
  LOAD(0, ka0, ka1, va0, va1);
  int kt = 0;
  for (;;) {
    ASM_VMCNT0();
    __syncthreads();
    WRITE(ka0, ka1, va0, va1);
    if (kt + 1 < NT) LOAD(kt + 1, kb0, kb1, vb0, vb1);
    __syncthreads();
    attn_tile(kt, qtB, qgB, qfB0, qfB1, accB, mB, lB, pwB, KsB, VTsB, g, l15, xr);
    if (kt <= qtA)
      attn_tile(kt, qtA, qgA, qfA0, qfA1, accA, mA, lA, pwA, KsB, VTsB, g, l15, xr);
    if (++kt >= NT) break;

    ASM_VMCNT0();
    __syncthreads();
    WRITE(kb0, kb1, vb0, vb1);
    if (kt + 1 < NT) LOAD(kt + 1, ka0, ka1, va0, va1);
    __syncthreads();
    attn_tile(kt, qtB, qgB, qfB0, qfB1, accB, mB, lB, pwB, KsB, VTsB, g, l15, xr);
    if (kt <= qtA)
      attn_tile(kt, qtA, qgA, qfA0, qfA1, accA, mA, lA, pwA, KsB, VTsB, g, l15, xr);
    if (++kt >= NT) break;
  }

  float liA[4], liB[4];
#pragma unroll
  for (int r = 0; r < 4; ++r) {
    liA[r] = 1.0f / __shfl(lA, g * 4 + r);
    liB[r] = 1.0f / __shfl(lB, g * 4 + r);
  }
#pragma unroll
  for (int nf = 0; nf < 4; ++nf)
#pragma unroll
    for (int r = 0; r < 4; ++r) {
      const int rowA = qtA * 64 + w * 16 + 4 * g + r;
      const int rowB = qtB * 64 + w * 16 + 4 * g + r;
      ctx[((size_t)(bb * 2048 + rowA)) * DD + hh * 64 + nf * 16 + l15] =
          (__bf16)(accA[nf][r] * liA[r]);
      ctx[((size_t)(bb * 2048 + rowB)) * DD + hh * 64 + nf * 16 + l15] =
          (__bf16)(accB[nf][r] * liB[r]);
    }
}

// ---------------- launcher ----------------
extern "C" void kernel_launch(void* const* d_in, const int* in_sizes, int n_in,
                              void* d_out, int out_size, void* d_ws, size_t ws_size,
                              hipStream_t stream)
{
  (void)in_sizes; (void)n_in; (void)out_size; (void)ws_size;
  const float* x  = (const float*)d_in[0];
  const float* wq = (const float*)d_in[1];
  const float* wk = (const float*)d_in[2];
  const float* wv = (const float*)d_in[3];
  const float* wo = (const float*)d_in[4];
  const float* bo = (const float*)d_in[5];
  const float* w1 = (const float*)d_in[6];
  const float* b1 = (const float*)d_in[7];
  const float* w2 = (const float*)d_in[8];
  const float* b2 = (const float*)d_in[9];
  const float* g1 = (const float*)d_in[10];
  const float* s1 = (const float*)d_in[11];
  const float* g2 = (const float*)d_in[12];
  const float* s2 = (const float*)d_in[13];
  float* out = (float*)d_out;

  char* ws = (char*)d_ws;
  __bf16* wbf  = (__bf16*)ws;                         // 24MB weights (q,k,v,o,w1,w2)
  __bf16* hbuf = (__bf16*)(ws + 25165824);            // 8MB
  __bf16* qkb  = (__bf16*)(ws + 33554432);            // 16MB, Q|K [4096][2048]
  __bf16* vbT  = (__bf16*)(ws + 50331648);            // 8MB,  V^T [2][16][64][2048]
  __bf16* ctxb = (__bf16*)(ws + 58720256);            // 8MB
  float*  x2   = (float*)(ws + 67108864);             // 16MB
  __bf16* ffb  = (__bf16*)(ws + 83886080);            // 32MB
  __bf16* part = (__bf16*)(ws + 33554432);            // 32MB, overlaps qkb..ctxb (dead post-WO)

  cvt_weights<<<12288, 256, 0, stream>>>(wq, wk, wv, wo, w1, w2, wbf);
  ln_kernel<<<1024, 256, 0, stream>>>(x, g1, s1, hbuf);

  // fused QKV: M=4096 N=3072 K=1024 (V transposed, Q pre-scaled in epilogue)
  gemm256<0><<<dim3(12, 16), 512, 0, stream>>>(
      hbuf, 1024, wbf, 1024, qkb, nullptr, vbT, NTOK, 3072, 1024);

  dim3 ga(16, 16, 2);
  attn_kernel<<<ga, 256, 0, stream>>>(qkb, vbT, ctxb);

  // WO: M=4096 N=1024 K=1024 (+bo, +x residual, f32)
  gemm_bt<true, true><<<dim3(8, 32), 256, 0, stream>>>(
      ctxb, wbf + 3145728, x2, bo, x, NTOK, DD, DD);
  ln_kernel<<<1024, 256, 0, stream>>>(x2, g2, s2, hbuf);

  // FF1: M=4096 N=4096 K=1024, bias+gelu -> bf16
  gemm256<1><<<dim3(16, 16), 512, 0, stream>>>(
      hbuf, 1024, wbf + 4194304, 1024, ffb, b1, nullptr, NTOK, FFD, 1024);

  // FF2 split-K (KS=4): bf16 partials, then fused reduce (+b2, +x2)
  gemm256<2><<<dim3(4, 16, 4), 512, 0, stream>>>(
      ffb, 4096, wbf + 8388608, 4096, part, nullptr, nullptr, NTOK, DD, 1024);
  ff2_reduce<<<4096, 256, 0, stream>>>(part, x2, b2, out);
}